// Round 2
// baseline (339.968 us; speedup 1.0000x reference)
//
#include <hip/hip_runtime.h>
#include <hip/hip_bf16.h>

// Fused attention block: QKV proj -> causal flash attention -> out proj.
// R1: + attn K-LDS XOR swizzle (T2, both-sides involution w/ global_load_lds),
//     diagonal-tile peel, explicit lgkmcnt(0) before cross-lane P reads,
//     XCD swizzle (T1) on all grids, fused cvt launches (8->5 dispatches).

typedef unsigned short u16;
typedef unsigned int   u32;
typedef __attribute__((ext_vector_type(8))) short bf16x8;
typedef __attribute__((ext_vector_type(4))) float f32x4;

#define AS1 __attribute__((address_space(1)))
#define AS3 __attribute__((address_space(3)))

__device__ __forceinline__ u16 f2bf(float f) {
  u32 x = __float_as_uint(f);
  x += 0x7fffu + ((x >> 16) & 1u);
  return (u16)(x >> 16);
}

// ---------- fused fp32->bf16 conversion for X, Wq, Wk, Wv, Wo ----------
// ranges (in float4 units): X 2097152 | Wq 262144 | Wk | Wv | Wo
__global__ __launch_bounds__(256) void cvt_all(const float* __restrict__ hs,
                                               const float* __restrict__ Wq,
                                               const float* __restrict__ Wk,
                                               const float* __restrict__ Wv,
                                               const float* __restrict__ Wo,
                                               u16* __restrict__ Xb,
                                               u16* __restrict__ Wqkv,
                                               u16* __restrict__ Wob) {
  int i = blockIdx.x * 256 + threadIdx.x;
  const int stride = gridDim.x * 256;
  for (; i < 3145728; i += stride) {
    const float* src;
    u16* dst;
    int off;
    if (i < 2097152) {
      src = hs; dst = Xb; off = i;
    } else {
      int j = i - 2097152;
      int m = j >> 18;            // 0..3
      off = j & 262143;
      src = (m == 0) ? Wq : (m == 1) ? Wk : (m == 2) ? Wv : Wo;
      dst = (m < 3) ? (Wqkv + (size_t)m * 1048576) : Wob;
    }
    float4 v = ((const float4*)src)[off];
    u32 lo = (u32)f2bf(v.x) | ((u32)f2bf(v.y) << 16);
    u32 hi = (u32)f2bf(v.z) | ((u32)f2bf(v.w) << 16);
    ((u32*)dst)[off * 2]     = lo;
    ((u32*)dst)[off * 2 + 1] = hi;
  }
}

// bias_qkv[0:1024]=bq, [1024:2048]=0, [2048:3072]=bv
__global__ __launch_bounds__(256) void build_bias(const float* __restrict__ bq,
                                                  const float* __restrict__ bv,
                                                  float* __restrict__ bias) {
  int i = blockIdx.x * blockDim.x + threadIdx.x;
  if (i >= 3072) return;
  float v = 0.f;
  if (i < 1024) v = bq[i];
  else if (i >= 2048) v = bv[i - 2048];
  bias[i] = v;
}

// ---------------- bf16 NT GEMM (m97 structure, 128x128, BK=32) -------------
// C[m][n] = sum_k A[m][k]*B[n][k] + bias[n].  1D grid + XCD swizzle.
template <int OUT_MODE>
__global__ __launch_bounds__(256) void gemm_nt(const u16* __restrict__ A,
                                               const u16* __restrict__ Bw,
                                               const float* __restrict__ bias,
                                               void* __restrict__ C,
                                               int M, int N, int K, int nbn) {
  __shared__ __align__(16) u16 As[128 * 32];
  __shared__ __align__(16) u16 Bs[128 * 32];
  const int cpx = gridDim.x >> 3;
  const int swz = (blockIdx.x & 7) * cpx + (blockIdx.x >> 3);
  const int bn = swz % nbn, bm = swz / nbn;
  const int tid = threadIdx.x;
  const int l = tid & 63, w = tid >> 6;
  const int l15 = l & 15, lg = l >> 4;
  const int wr = w >> 1, wc = w & 1;

  f32x4 acc[4][4] = {};

  const u16* Ab = A + (size_t)(bm * 128) * K;
  const u16* Bb = Bw + (size_t)(bn * 128) * K;

  const int srow = w * 16 + (l >> 2);
  const int sk = (l & 3) * 8;

  for (int k0 = 0; k0 < K; k0 += 32) {
#pragma unroll
    for (int i = 0; i < 2; ++i) {
      int row = i * 64 + srow;
      __builtin_amdgcn_global_load_lds(
          (const AS1 void*)(Ab + (size_t)row * K + k0 + sk),
          (AS3 void*)((AS3 u16*)As + i * 2048 + w * 512), 16, 0, 0);
      __builtin_amdgcn_global_load_lds(
          (const AS1 void*)(Bb + (size_t)row * K + k0 + sk),
          (AS3 void*)((AS3 u16*)Bs + i * 2048 + w * 512), 16, 0, 0);
    }
    __syncthreads();
    bf16x8 af[4], bf[4];
#pragma unroll
    for (int m = 0; m < 4; ++m)
      af[m] = *(const bf16x8*)&As[(wr * 64 + m * 16 + l15) * 32 + lg * 8];
#pragma unroll
    for (int n = 0; n < 4; ++n)
      bf[n] = *(const bf16x8*)&Bs[(wc * 64 + n * 16 + l15) * 32 + lg * 8];
#pragma unroll
    for (int m = 0; m < 4; ++m)
#pragma unroll
      for (int n = 0; n < 4; ++n)
        acc[m][n] = __builtin_amdgcn_mfma_f32_16x16x32_bf16(af[m], bf[n], acc[m][n], 0, 0, 0);
    __syncthreads();
  }

  // epilogue: C/D layout col=lane&15, row=(lane>>4)*4+reg
#pragma unroll
  for (int m = 0; m < 4; ++m) {
#pragma unroll
    for (int i = 0; i < 4; ++i) {
      int row = bm * 128 + wr * 64 + m * 16 + lg * 4 + i;
#pragma unroll
      for (int n = 0; n < 4; ++n) {
        int col = bn * 128 + wc * 64 + n * 16 + l15;
        float v = acc[m][n][i] + bias[col];
        if (OUT_MODE == 0)
          ((u16*)C)[(size_t)row * N + col] = f2bf(v);
        else
          ((float*)C)[(size_t)row * N + col] = v;
      }
    }
  }
}

// ---------------- flash attention (causal, S=1024, D=64, 16 heads) --------
// qkv: [8192][3072] bf16 rows (q | k | v). Block: (seq, head, qtile of 64);
// 4 waves x 16 q rows. K tile XOR-swizzled in LDS (T2 involution).
template <bool DIAG>
__device__ __forceinline__ void attn_tile(const u16* __restrict__ kbase,
                                          const u16* __restrict__ vbase,
                                          u16* __restrict__ Ks, u16* __restrict__ Vt,
                                          u16* __restrict__ ps,
                                          const bf16x8 (&qf)[2], f32x4 (&o_acc)[4],
                                          float (&m_r)[4], float (&l_r)[4],
                                          int tid, int qpos, int kvpos0) {
  const int l = tid & 63, w = tid >> 6;
  const int l15 = l & 15, lg = l >> 4;

  // ---- stage K [64][64] via global_load_lds, source-chunk pre-swizzled ----
  // LDS[row][ch] = K[row][ch ^ (row&7)] (16B chunks); read XORs back.
#pragma unroll
  for (int i = 0; i < 2; ++i) {
    int row = i * 32 + w * 8 + (l >> 3);
    int schunk = (l & 7) ^ ((l >> 3) & 7);
    __builtin_amdgcn_global_load_lds(
        (const AS1 void*)(kbase + (size_t)row * 3072 + schunk * 8),
        (AS3 void*)((AS3 u16*)Ks + i * 2048 + w * 512), 16, 0, 0);
  }
  // ---- stage V transposed: Vt[d][kv], pad 72 ----
#pragma unroll
  for (int i = 0; i < 2; ++i) {
    int lin = tid + i * 256;
    int kv = lin >> 3;
    int dofs = (lin & 7) * 8;
    bf16x8 v = *(const bf16x8*)(vbase + (size_t)kv * 3072 + dofs);
#pragma unroll
    for (int j = 0; j < 8; ++j) Vt[(dofs + j) * 72 + kv] = (u16)v[j];
  }
  __syncthreads();

  // ---- QK^T ----
  f32x4 sc[4] = {};
#pragma unroll
  for (int c = 0; c < 2; ++c)
#pragma unroll
    for (int n = 0; n < 4; ++n) {
      int row = n * 16 + l15;
      int ch = ((c * 4 + lg) ^ (l15 & 7)) * 8;   // swizzled 16B-chunk
      bf16x8 b = *(const bf16x8*)&Ks[row * 64 + ch];
      sc[n] = __builtin_amdgcn_mfma_f32_16x16x32_bf16(qf[c], b, sc[n], 0, 0, 0);
    }

  // ---- scale + (diag) mask + online softmax ----
  float pmax[4];
#pragma unroll
  for (int i = 0; i < 4; ++i) {
    float mx = -1e30f;
#pragma unroll
    for (int n = 0; n < 4; ++n) {
      float v = sc[n][i] * 0.125f;
      if (DIAG) {
        int kvpos = kvpos0 + n * 16 + l15;
        if (kvpos > qpos + i) v = -1e30f;
      }
      sc[n][i] = v;
      mx = fmaxf(mx, v);
    }
    pmax[i] = mx;
  }
#pragma unroll
  for (int d = 1; d < 16; d <<= 1)
#pragma unroll
    for (int i = 0; i < 4; ++i)
      pmax[i] = fmaxf(pmax[i], __shfl_xor(pmax[i], d, 64));

  float alpha[4];
#pragma unroll
  for (int i = 0; i < 4; ++i) {
    float mn = fmaxf(m_r[i], pmax[i]);
    alpha[i] = __expf(m_r[i] - mn);
    m_r[i] = mn;
  }
  float rs[4] = {0.f, 0.f, 0.f, 0.f};
#pragma unroll
  for (int n = 0; n < 4; ++n)
#pragma unroll
    for (int i = 0; i < 4; ++i) {
      float p = __expf(sc[n][i] - m_r[i]);
      sc[n][i] = p;
      rs[i] += p;
    }
#pragma unroll
  for (int d = 1; d < 16; d <<= 1)
#pragma unroll
    for (int i = 0; i < 4; ++i) rs[i] += __shfl_xor(rs[i], d, 64);
#pragma unroll
  for (int i = 0; i < 4; ++i) l_r[i] = l_r[i] * alpha[i] + rs[i];
#pragma unroll
  for (int f = 0; f < 4; ++f)
#pragma unroll
    for (int i = 0; i < 4; ++i) o_acc[f][i] *= alpha[i];

  // ---- P -> per-wave LDS (re-fragment) ----
#pragma unroll
  for (int n = 0; n < 4; ++n)
#pragma unroll
    for (int i = 0; i < 4; ++i)
      ps[(lg * 4 + i) * 72 + n * 16 + l15] = f2bf(sc[n][i]);
  // cross-lane LDS write->read within the wave: drain DS queue explicitly
  asm volatile("s_waitcnt lgkmcnt(0)" ::: "memory");

  bf16x8 pa[2];
  pa[0] = *(const bf16x8*)&ps[l15 * 72 + lg * 8];
  pa[1] = *(const bf16x8*)&ps[l15 * 72 + 32 + lg * 8];
#pragma unroll
  for (int c = 0; c < 2; ++c)
#pragma unroll
    for (int f = 0; f < 4; ++f) {
      bf16x8 bv_ = *(const bf16x8*)&Vt[(f * 16 + l15) * 72 + c * 32 + lg * 8];
      o_acc[f] = __builtin_amdgcn_mfma_f32_16x16x32_bf16(pa[c], bv_, o_acc[f], 0, 0, 0);
    }
  __syncthreads();
}

__global__ __launch_bounds__(256) void attn_kernel(const u16* __restrict__ qkv,
                                                   u16* __restrict__ attnout) {
  // XCD swizzle: all 16 q-tiles of one (s,h) — which share K/V — on one XCD
  const int bid = (blockIdx.x & 7) * 256 + (blockIdx.x >> 3);
  const int qt = bid & 15;
  const int h = (bid >> 4) & 15;
  const int s = bid >> 8;
  const int tid = threadIdx.x;
  const int l = tid & 63, w = tid >> 6;
  const int l15 = l & 15, lg = l >> 4;

  __shared__ __align__(16) u16 Ks[64 * 64];
  __shared__ __align__(16) u16 Vt[64 * 72];
  __shared__ __align__(16) u16 Ps[4 * 16 * 72];

  bf16x8 qf[2];
  {
    const u16* qptr = qkv + (size_t)(s * 1024 + qt * 64 + w * 16 + l15) * 3072 + h * 64 + lg * 8;
    qf[0] = *(const bf16x8*)qptr;
    qf[1] = *(const bf16x8*)(qptr + 32);
  }

  float m_r[4], l_r[4];
  f32x4 o_acc[4] = {};
#pragma unroll
  for (int i = 0; i < 4; ++i) { m_r[i] = -1e30f; l_r[i] = 0.f; }

  const int qpos = qt * 64 + w * 16 + lg * 4;
  const u16* base = qkv + (size_t)(s * 1024) * 3072;
  u16* ps = Ps + w * 16 * 72;

  for (int kvb = 0; kvb < qt; ++kvb)
    attn_tile<false>(base + (size_t)(kvb * 64) * 3072 + 1024 + h * 64,
                     base + (size_t)(kvb * 64) * 3072 + 2048 + h * 64,
                     Ks, Vt, ps, qf, o_acc, m_r, l_r, tid, qpos, kvb * 64);
  attn_tile<true>(base + (size_t)(qt * 64) * 3072 + 1024 + h * 64,
                  base + (size_t)(qt * 64) * 3072 + 2048 + h * 64,
                  Ks, Vt, ps, qf, o_acc, m_r, l_r, tid, qpos, qt * 64);

#pragma unroll
  for (int f = 0; f < 4; ++f)
#pragma unroll
    for (int i = 0; i < 4; ++i) {
      float o = o_acc[f][i] / l_r[i];
      int trow = s * 1024 + qt * 64 + w * 16 + lg * 4 + i;
      attnout[(size_t)trow * 1024 + h * 64 + f * 16 + l15] = f2bf(o);
    }
}

// ---------------- host launch ----------------
extern "C" void kernel_launch(void* const* d_in, const int* in_sizes, int n_in,
                              void* d_out, int out_size, void* d_ws, size_t ws_size,
                              hipStream_t stream) {
  const float* hs = (const float*)d_in[0];
  // d_in[1] = seq_len (int64, all 1024) — fixed shape, hardcoded
  const float* Wq = (const float*)d_in[2];
  const float* bq = (const float*)d_in[3];
  const float* Wk = (const float*)d_in[4];
  const float* Wv = (const float*)d_in[5];
  const float* bv = (const float*)d_in[6];
  const float* Wo = (const float*)d_in[7];
  const float* bo = (const float*)d_in[8];

  char* ws = (char*)d_ws;
  u16* Xb    = (u16*)ws;                    // 8192x1024 bf16 = 16 MB
  u16* Wqkv  = (u16*)(ws + 16777216);       // 3072x1024 bf16 = 6 MB
  u16* Wob   = (u16*)(ws + 23068672);       // 1024x1024 bf16 = 2 MB
  float* bqk = (float*)(ws + 25165824);     // 3072 f32
  u16* qkv   = (u16*)(ws + 25178112);       // 8192x3072 bf16 = 48 MB
  u16* attn  = (u16*)(ws + 75509760);       // 8192x1024 bf16 = 16 MB

  cvt_all<<<2048, 256, 0, stream>>>(hs, Wq, Wk, Wv, Wo, Xb, Wqkv, Wob);
  build_bias<<<12, 256, 0, stream>>>(bq, bv, bqk);

  gemm_nt<0><<<1536, 256, 0, stream>>>(Xb, Wqkv, bqk, qkv, 8192, 3072, 1024, 24);

  attn_kernel<<<2048, 256, 0, stream>>>(qkv, attn);

  gemm_nt<1><<<512, 256, 0, stream>>>(attn, Wob, bo, d_out, 8192, 1024, 1024, 8);
}

// Round 3
// 326.290 us; speedup vs baseline: 1.0419x; 1.0419x over previous
//
#include <hip/hip_runtime.h>
#include <hip/hip_bf16.h>

// Fused attention block: QKV proj -> causal flash attention -> out proj.
// R2: attn KVBLK=128, pair-packed V staging (2-way banks), Ps pad 130,
//     V early-issue (T14), qt-descending launch order. GEMMs unchanged.

typedef unsigned short u16;
typedef unsigned int   u32;
typedef __attribute__((ext_vector_type(8))) short bf16x8;
typedef __attribute__((ext_vector_type(4))) float f32x4;
typedef __attribute__((ext_vector_type(4))) u32 u32x4;

#define AS1 __attribute__((address_space(1)))
#define AS3 __attribute__((address_space(3)))

__device__ __forceinline__ u16 f2bf(float f) {
  u32 x = __float_as_uint(f);
  x += 0x7fffu + ((x >> 16) & 1u);
  return (u16)(x >> 16);
}

// ---------- fused fp32->bf16 conversion for X, Wq, Wk, Wv, Wo ----------
__global__ __launch_bounds__(256) void cvt_all(const float* __restrict__ hs,
                                               const float* __restrict__ Wq,
                                               const float* __restrict__ Wk,
                                               const float* __restrict__ Wv,
                                               const float* __restrict__ Wo,
                                               u16* __restrict__ Xb,
                                               u16* __restrict__ Wqkv,
                                               u16* __restrict__ Wob) {
  int i = blockIdx.x * 256 + threadIdx.x;
  const int stride = gridDim.x * 256;
  for (; i < 3145728; i += stride) {
    const float* src;
    u16* dst;
    int off;
    if (i < 2097152) {
      src = hs; dst = Xb; off = i;
    } else {
      int j = i - 2097152;
      int m = j >> 18;
      off = j & 262143;
      src = (m == 0) ? Wq : (m == 1) ? Wk : (m == 2) ? Wv : Wo;
      dst = (m < 3) ? (Wqkv + (size_t)m * 1048576) : Wob;
    }
    float4 v = ((const float4*)src)[off];
    u32 lo = (u32)f2bf(v.x) | ((u32)f2bf(v.y) << 16);
    u32 hi = (u32)f2bf(v.z) | ((u32)f2bf(v.w) << 16);
    ((u32*)dst)[off * 2]     = lo;
    ((u32*)dst)[off * 2 + 1] = hi;
  }
}

__global__ __launch_bounds__(256) void build_bias(const float* __restrict__ bq,
                                                  const float* __restrict__ bv,
                                                  float* __restrict__ bias) {
  int i = blockIdx.x * blockDim.x + threadIdx.x;
  if (i >= 3072) return;
  float v = 0.f;
  if (i < 1024) v = bq[i];
  else if (i >= 2048) v = bv[i - 2048];
  bias[i] = v;
}

// ---------------- bf16 NT GEMM (m97 structure, 128x128, BK=32) -------------
template <int OUT_MODE>
__global__ __launch_bounds__(256) void gemm_nt(const u16* __restrict__ A,
                                               const u16* __restrict__ Bw,
                                               const float* __restrict__ bias,
                                               void* __restrict__ C,
                                               int M, int N, int K, int nbn) {
  __shared__ __align__(16) u16 As[128 * 32];
  __shared__ __align__(16) u16 Bs[128 * 32];
  const int cpx = gridDim.x >> 3;
  const int swz = (blockIdx.x & 7) * cpx + (blockIdx.x >> 3);
  const int bn = swz % nbn, bm = swz / nbn;
  const int tid = threadIdx.x;
  const int l = tid & 63, w = tid >> 6;
  const int l15 = l & 15, lg = l >> 4;
  const int wr = w >> 1, wc = w & 1;

  f32x4 acc[4][4] = {};

  const u16* Ab = A + (size_t)(bm * 128) * K;
  const u16* Bb = Bw + (size_t)(bn * 128) * K;

  const int srow = w * 16 + (l >> 2);
  const int sk = (l & 3) * 8;

  for (int k0 = 0; k0 < K; k0 += 32) {
#pragma unroll
    for (int i = 0; i < 2; ++i) {
      int row = i * 64 + srow;
      __builtin_amdgcn_global_load_lds(
          (const AS1 void*)(Ab + (size_t)row * K + k0 + sk),
          (AS3 void*)((AS3 u16*)As + i * 2048 + w * 512), 16, 0, 0);
      __builtin_amdgcn_global_load_lds(
          (const AS1 void*)(Bb + (size_t)row * K + k0 + sk),
          (AS3 void*)((AS3 u16*)Bs + i * 2048 + w * 512), 16, 0, 0);
    }
    __syncthreads();
    bf16x8 af[4], bf[4];
#pragma unroll
    for (int m = 0; m < 4; ++m)
      af[m] = *(const bf16x8*)&As[(wr * 64 + m * 16 + l15) * 32 + lg * 8];
#pragma unroll
    for (int n = 0; n < 4; ++n)
      bf[n] = *(const bf16x8*)&Bs[(wc * 64 + n * 16 + l15) * 32 + lg * 8];
#pragma unroll
    for (int m = 0; m < 4; ++m)
#pragma unroll
      for (int n = 0; n < 4; ++n)
        acc[m][n] = __builtin_amdgcn_mfma_f32_16x16x32_bf16(af[m], bf[n], acc[m][n], 0, 0, 0);
    __syncthreads();
  }

#pragma unroll
  for (int m = 0; m < 4; ++m) {
#pragma unroll
    for (int i = 0; i < 4; ++i) {
      int row = bm * 128 + wr * 64 + m * 16 + lg * 4 + i;
#pragma unroll
      for (int n = 0; n < 4; ++n) {
        int col = bn * 128 + wc * 64 + n * 16 + l15;
        float v = acc[m][n][i] + bias[col];
        if (OUT_MODE == 0)
          ((u16*)C)[(size_t)row * N + col] = f2bf(v);
        else
          ((float*)C)[(size_t)row * N + col] = v;
      }
    }
  }
}

// ---------------- flash attention (causal, S=1024, D=64, 16 heads) --------
// qkv rows: [8192][3072] bf16 (q | k | v). Block: (s, h, qtile of 64 rows),
// 4 waves x 16 q rows, KVBLK=128. K XOR-swizzled LDS; V pair-packed u32 LDS.
__global__ __launch_bounds__(256) void attn_kernel(const u16* __restrict__ qkv,
                                                   u16* __restrict__ attnout) {
  const int bid = (blockIdx.x & 7) * 256 + (blockIdx.x >> 3);  // XCD swizzle
  const int qt = 15 - (bid & 15);                              // longest-first
  const int h = (bid >> 4) & 15;
  const int s = bid >> 8;
  const int tid = threadIdx.x;
  const int l = tid & 63, w = tid >> 6;
  const int l15 = l & 15, lg = l >> 4;
  const int pb = (l >> 3) & 1;                                 // kv parity

  __shared__ __align__(16) u16 Ks[128 * 64];      // swizzled [kv][d]
  __shared__ __align__(16) u32 Vt2[64 * 65];      // [d][kvpair], pad 65
  __shared__ __align__(16) u16 Ps[4 * 16 * 130];  // per-wave P [16][130]

  bf16x8 qf[2];
  {
    const u16* qptr = qkv + (size_t)(s * 1024 + qt * 64 + w * 16 + l15) * 3072 + h * 64 + lg * 8;
    qf[0] = *(const bf16x8*)qptr;
    qf[1] = *(const bf16x8*)(qptr + 32);
  }

  float m_r[4], l_r[4];
  f32x4 o_acc[4] = {};
#pragma unroll
  for (int i = 0; i < 4; ++i) { m_r[i] = -1e30f; l_r[i] = 0.f; }

  const int qpos = qt * 64 + w * 16 + lg * 4;
  const u16* kbase = qkv + (size_t)(s * 1024) * 3072 + 1024 + h * 64;
  const u16* vbase = qkv + (size_t)(s * 1024) * 3072 + 2048 + h * 64;
  u16* ps = Ps + w * 16 * 130;

  const int nt = (qt >> 1) + 1;

  // V source coords for this thread (per pass p): kv = p*32 + w*8 + (l>>3)
  const int vkv_base = w * 8 + (l >> 3);
  const int vd0 = (l & 7) * 8;
  const int vkp = w * 4 + (l >> 4);  // + p*16

  bf16x8 vcur[4], vnext[4];
#pragma unroll
  for (int p = 0; p < 4; ++p)
    vcur[p] = *(const bf16x8*)(vbase + (size_t)(p * 32 + vkv_base) * 3072 + vd0);

  for (int t = 0; t < nt; ++t) {
    // ---- stage K tile [128][64] via global_load_lds, source pre-swizzled ----
    const u16* kt = kbase + (size_t)(t * 128) * 3072;
    {
      const int row = w * 8 + (l >> 3);
      const int schunk = (l & 7) ^ ((l >> 3) & 7);
#pragma unroll
      for (int p = 0; p < 4; ++p)
        __builtin_amdgcn_global_load_lds(
            (const AS1 void*)(kt + (size_t)(p * 32 + row) * 3072 + schunk * 8),
            (AS3 void*)((AS3 u16*)Ks + p * 2048 + w * 512), 16, 0, 0);
    }
    // ---- pack + write V (pair lanes kv, kv^1 exchange halves) ----
#pragma unroll
    for (int p = 0; p < 4; ++p) {
      u32 dw0 = ((u32*)&vcur[p])[0], dw1 = ((u32*)&vcur[p])[1];
      u32 dw2 = ((u32*)&vcur[p])[2], dw3 = ((u32*)&vcur[p])[3];
      u32 s0 = (u32)__shfl_xor((int)(pb ? dw0 : dw2), 8, 64);
      u32 s1 = (u32)__shfl_xor((int)(pb ? dw1 : dw3), 8, 64);
      u32 md0 = pb ? dw2 : dw0, md1 = pb ? dw3 : dw1;
      u32 lo0 = pb ? s0 : md0, hi0 = pb ? md0 : s0;
      u32 lo1 = pb ? s1 : md1, hi1 = pb ? md1 : s1;
      int dEff = vd0 + pb * 4;
      int kp = p * 16 + vkp;
      Vt2[(dEff + 0) * 65 + kp] = (lo0 & 0xffffu) | (hi0 << 16);
      Vt2[(dEff + 1) * 65 + kp] = (lo0 >> 16) | (hi0 & 0xffff0000u);
      Vt2[(dEff + 2) * 65 + kp] = (lo1 & 0xffffu) | (hi1 << 16);
      Vt2[(dEff + 3) * 65 + kp] = (lo1 >> 16) | (hi1 & 0xffff0000u);
    }
    __syncthreads();  // drains K glds (vmcnt) + V writes (lgkm)

    // ---- QK^T: 16 q rows x 128 kv ----
    f32x4 sc[8] = {};
#pragma unroll
    for (int c = 0; c < 2; ++c)
#pragma unroll
      for (int n = 0; n < 8; ++n) {
        int row = n * 16 + l15;
        int ch = (c * 4 + lg) ^ (l15 & 7);
        bf16x8 b = *(const bf16x8*)&Ks[row * 64 + ch * 8];
        sc[n] = __builtin_amdgcn_mfma_f32_16x16x32_bf16(qf[c], b, sc[n], 0, 0, 0);
      }

    // ---- early-issue next tile's V loads (latency hides under softmax+PV) --
    if (t + 1 < nt) {
      const u16* vt = vbase + (size_t)((t + 1) * 128) * 3072;
#pragma unroll
      for (int p = 0; p < 4; ++p)
        vnext[p] = *(const bf16x8*)(vt + (size_t)(p * 32 + vkv_base) * 3072 + vd0);
    }

    // ---- scale + (diag) mask + online softmax ----
    const bool diag = (t == nt - 1);
    float pmax[4];
#pragma unroll
    for (int i = 0; i < 4; ++i) {
      float mx = -1e30f;
#pragma unroll
      for (int n = 0; n < 8; ++n) {
        float v = sc[n][i] * 0.125f;
        if (diag) {
          int kvpos = t * 128 + n * 16 + l15;
          if (kvpos > qpos + i) v = -1e30f;
        }
        sc[n][i] = v;
        mx = fmaxf(mx, v);
      }
      pmax[i] = mx;
    }
#pragma unroll
    for (int d = 1; d < 16; d <<= 1)
#pragma unroll
      for (int i = 0; i < 4; ++i)
        pmax[i] = fmaxf(pmax[i], __shfl_xor(pmax[i], d, 64));

    float alpha[4];
#pragma unroll
    for (int i = 0; i < 4; ++i) {
      float mn = fmaxf(m_r[i], pmax[i]);
      alpha[i] = __expf(m_r[i] - mn);
      m_r[i] = mn;
    }
    float rs[4] = {0.f, 0.f, 0.f, 0.f};
#pragma unroll
    for (int n = 0; n < 8; ++n)
#pragma unroll
      for (int i = 0; i < 4; ++i) {
        float p = __expf(sc[n][i] - m_r[i]);
        sc[n][i] = p;
        rs[i] += p;
      }
#pragma unroll
    for (int d = 1; d < 16; d <<= 1)
#pragma unroll
      for (int i = 0; i < 4; ++i) rs[i] += __shfl_xor(rs[i], d, 64);
#pragma unroll
    for (int i = 0; i < 4; ++i) l_r[i] = l_r[i] * alpha[i] + rs[i];
#pragma unroll
    for (int f = 0; f < 4; ++f)
#pragma unroll
      for (int i = 0; i < 4; ++i) o_acc[f][i] *= alpha[i];

    // ---- P -> per-wave LDS (re-fragment) ----
#pragma unroll
    for (int n = 0; n < 8; ++n)
#pragma unroll
      for (int i = 0; i < 4; ++i)
        ps[(lg * 4 + i) * 130 + n * 16 + l15] = f2bf(sc[n][i]);
    asm volatile("s_waitcnt lgkmcnt(0)" ::: "memory");

    bf16x8 pa[4];
#pragma unroll
    for (int c = 0; c < 4; ++c)
      pa[c] = *(const bf16x8*)&ps[l15 * 130 + c * 32 + lg * 8];

    // ---- PV ----
#pragma unroll
    for (int f = 0; f < 4; ++f)
#pragma unroll
      for (int c = 0; c < 4; ++c) {
        u32x4 vv = *(const u32x4*)&Vt2[(f * 16 + l15) * 65 + c * 16 + lg * 4];
        o_acc[f] = __builtin_amdgcn_mfma_f32_16x16x32_bf16(
            pa[c], *(const bf16x8*)&vv, o_acc[f], 0, 0, 0);
      }
    __syncthreads();

#pragma unroll
    for (int p = 0; p < 4; ++p) vcur[p] = vnext[p];
  }

  // ---- epilogue ----
#pragma unroll
  for (int f = 0; f < 4; ++f)
#pragma unroll
    for (int i = 0; i < 4; ++i) {
      float o = o_acc[f][i] / l_r[i];
      int trow = s * 1024 + qt * 64 + w * 16 + lg * 4 + i;
      attnout[(size_t)trow * 1024 + h * 64 + f * 16 + l15] = f2bf(o);
    }
}

// ---------------- host launch ----------------
extern "C" void kernel_launch(void* const* d_in, const int* in_sizes, int n_in,
                              void* d_out, int out_size, void* d_ws, size_t ws_size,
                              hipStream_t stream) {
  const float* hs = (const float*)d_in[0];
  const float* Wq = (const float*)d_in[2];
  const float* bq = (const float*)d_in[3];
  const float* Wk = (const float*)d_in[4];
  const float* Wv = (const float*)d_in[5];
  const float* bv = (const float*)d_in[6];
  const float* Wo = (const float*)d_in[7];
  const float* bo = (const float*)d_in[8];

  char* ws = (char*)d_ws;
  u16* Xb    = (u16*)ws;
  u16* Wqkv  = (u16*)(ws + 16777216);
  u16* Wob   = (u16*)(ws + 23068672);
  float* bqk = (float*)(ws + 25165824);
  u16* qkv   = (u16*)(ws + 25178112);
  u16* attn  = (u16*)(ws + 75509760);

  cvt_all<<<2048, 256, 0, stream>>>(hs, Wq, Wk, Wv, Wo, Xb, Wqkv, Wob);
  build_bias<<<12, 256, 0, stream>>>(bq, bv, bqk);

  gemm_nt<0><<<1536, 256, 0, stream>>>(Xb, Wqkv, bqk, qkv, 8192, 3072, 1024, 24);

  attn_kernel<<<2048, 256, 0, stream>>>(qkv, attn);

  gemm_nt<1><<<512, 256, 0, stream>>>(attn, Wob, bo, d_out, 8192, 1024, 1024, 8);
}

// Round 4
// 287.023 us; speedup vs baseline: 1.1845x; 1.1368x over previous
//
#include <hip/hip_runtime.h>
#include <hip/hip_bf16.h>

// Fused attention block: QKV proj -> causal flash attention -> out proj.
// R3: attention rewritten to swapped-QK^T 32x32x16 MFMA structure (m214/§B):
//     P-column lane-local -> in-register softmax (no P->LDS round trip, no
//     16-lane shfl reduces), defer-max (T13), in-reg P^T frag build via
//     pack+shfl_xor(32). K: XOR-swizzled global_load_lds; V: pair-packed Vt2
//     (both verified R2). 4 waves x 32q, KVBLK=128, LDS 33KB -> 4 blocks/CU.

typedef unsigned short u16;
typedef unsigned int   u32;
typedef __attribute__((ext_vector_type(8))) short bf16x8;
typedef __attribute__((ext_vector_type(4))) float f32x4;
typedef __attribute__((ext_vector_type(16))) float f32x16;
typedef __attribute__((ext_vector_type(4))) u32 u32x4;

#define AS1 __attribute__((address_space(1)))
#define AS3 __attribute__((address_space(3)))

__device__ __forceinline__ u16 f2bf(float f) {
  u32 x = __float_as_uint(f);
  x += 0x7fffu + ((x >> 16) & 1u);
  return (u16)(x >> 16);
}
__device__ __forceinline__ u32 pk2(float a, float b) {
  return (u32)f2bf(a) | ((u32)f2bf(b) << 16);
}

// ---------- fused fp32->bf16 conversion for X, Wq, Wk, Wv, Wo ----------
__global__ __launch_bounds__(256) void cvt_all(const float* __restrict__ hs,
                                               const float* __restrict__ Wq,
                                               const float* __restrict__ Wk,
                                               const float* __restrict__ Wv,
                                               const float* __restrict__ Wo,
                                               u16* __restrict__ Xb,
                                               u16* __restrict__ Wqkv,
                                               u16* __restrict__ Wob) {
  int i = blockIdx.x * 256 + threadIdx.x;
  const int stride = gridDim.x * 256;
  for (; i < 3145728; i += stride) {
    const float* src;
    u16* dst;
    int off;
    if (i < 2097152) {
      src = hs; dst = Xb; off = i;
    } else {
      int j = i - 2097152;
      int m = j >> 18;
      off = j & 262143;
      src = (m == 0) ? Wq : (m == 1) ? Wk : (m == 2) ? Wv : Wo;
      dst = (m < 3) ? (Wqkv + (size_t)m * 1048576) : Wob;
    }
    float4 v = ((const float4*)src)[off];
    u32 lo = (u32)f2bf(v.x) | ((u32)f2bf(v.y) << 16);
    u32 hi = (u32)f2bf(v.z) | ((u32)f2bf(v.w) << 16);
    ((u32*)dst)[off * 2]     = lo;
    ((u32*)dst)[off * 2 + 1] = hi;
  }
}

__global__ __launch_bounds__(256) void build_bias(const float* __restrict__ bq,
                                                  const float* __restrict__ bv,
                                                  float* __restrict__ bias) {
  int i = blockIdx.x * blockDim.x + threadIdx.x;
  if (i >= 3072) return;
  float v = 0.f;
  if (i < 1024) v = bq[i];
  else if (i >= 2048) v = bv[i - 2048];
  bias[i] = v;
}

// ---------------- bf16 NT GEMM (m97 structure, 128x128, BK=32) -------------
template <int OUT_MODE>
__global__ __launch_bounds__(256) void gemm_nt(const u16* __restrict__ A,
                                               const u16* __restrict__ Bw,
                                               const float* __restrict__ bias,
                                               void* __restrict__ C,
                                               int M, int N, int K, int nbn) {
  __shared__ __align__(16) u16 As[128 * 32];
  __shared__ __align__(16) u16 Bs[128 * 32];
  const int cpx = gridDim.x >> 3;
  const int swz = (blockIdx.x & 7) * cpx + (blockIdx.x >> 3);
  const int bn = swz % nbn, bm = swz / nbn;
  const int tid = threadIdx.x;
  const int l = tid & 63, w = tid >> 6;
  const int l15 = l & 15, lg = l >> 4;
  const int wr = w >> 1, wc = w & 1;

  f32x4 acc[4][4] = {};

  const u16* Ab = A + (size_t)(bm * 128) * K;
  const u16* Bb = Bw + (size_t)(bn * 128) * K;

  const int srow = w * 16 + (l >> 2);
  const int sk = (l & 3) * 8;

  for (int k0 = 0; k0 < K; k0 += 32) {
#pragma unroll
    for (int i = 0; i < 2; ++i) {
      int row = i * 64 + srow;
      __builtin_amdgcn_global_load_lds(
          (const AS1 void*)(Ab + (size_t)row * K + k0 + sk),
          (AS3 void*)((AS3 u16*)As + i * 2048 + w * 512), 16, 0, 0);
      __builtin_amdgcn_global_load_lds(
          (const AS1 void*)(Bb + (size_t)row * K + k0 + sk),
          (AS3 void*)((AS3 u16*)Bs + i * 2048 + w * 512), 16, 0, 0);
    }
    __syncthreads();
    bf16x8 af[4], bf[4];
#pragma unroll
    for (int m = 0; m < 4; ++m)
      af[m] = *(const bf16x8*)&As[(wr * 64 + m * 16 + l15) * 32 + lg * 8];
#pragma unroll
    for (int n = 0; n < 4; ++n)
      bf[n] = *(const bf16x8*)&Bs[(wc * 64 + n * 16 + l15) * 32 + lg * 8];
#pragma unroll
    for (int m = 0; m < 4; ++m)
#pragma unroll
      for (int n = 0; n < 4; ++n)
        acc[m][n] = __builtin_amdgcn_mfma_f32_16x16x32_bf16(af[m], bf[n], acc[m][n], 0, 0, 0);
    __syncthreads();
  }

#pragma unroll
  for (int m = 0; m < 4; ++m) {
#pragma unroll
    for (int i = 0; i < 4; ++i) {
      int row = bm * 128 + wr * 64 + m * 16 + lg * 4 + i;
#pragma unroll
      for (int n = 0; n < 4; ++n) {
        int col = bn * 128 + wc * 64 + n * 16 + l15;
        float v = acc[m][n][i] + bias[col];
        if (OUT_MODE == 0)
          ((u16*)C)[(size_t)row * N + col] = f2bf(v);
        else
          ((float*)C)[(size_t)row * N + col] = v;
      }
    }
  }
}

// ---------------- flash attention: swapped-QK^T 32x32 structure -----------
// qkv rows: [8192][3072] bf16 (q | k | v). Block: (s, h, qblock of 128 rows),
// 4 waves x 32 q rows each. S[kv][q] = mfma32x32(K,Q): lane owns q=l&31
// column, 16 kv per lane (+partner lane l^32). Softmax fully in-register.
__global__ __launch_bounds__(256, 4) void attn_kernel(const u16* __restrict__ qkv,
                                                      u16* __restrict__ attnout) {
  const int bid = (blockIdx.x & 7) * 128 + (blockIdx.x >> 3);  // XCD: 1 seq/XCD
  const int qb = 7 - (bid & 7);                                // longest first
  const int h = (bid >> 3) & 15;
  const int s = bid >> 7;
  const int tid = threadIdx.x;
  const int l = tid & 63, w = tid >> 6;
  const int l31 = l & 31;
  const int hi = l >> 5;
  const int pb = (l >> 3) & 1;

  __shared__ __align__(16) u16 Ks[128 * 64];   // XOR-swizzled [kv][d]
  __shared__ __align__(16) u32 Vt2[64 * 65];   // [d][kvpair], pad 65

  const u16* kbase = qkv + (size_t)(s * 1024) * 3072 + 1024 + h * 64;
  const u16* vbase = qkv + (size_t)(s * 1024) * 3072 + 2048 + h * 64;

  // Q frag (B operand): col=q=l31, k=d = c*16 + hi*8 + j
  bf16x8 qf[4];
  {
    const u16* qptr = qkv + (size_t)(s * 1024 + qb * 128 + w * 32 + l31) * 3072 + h * 64 + hi * 8;
#pragma unroll
    for (int c = 0; c < 4; ++c) qf[c] = *(const bf16x8*)(qptr + c * 16);
  }

  float m_r = -1e30f, l_r = 0.f;
  f32x16 o0 = {}, o1 = {};  // O[q][d]: dblk 0 (d=l31), dblk 1 (d=32+l31)

  const int nt = qb + 1;

  // V staging thread coords (verified R2): kv = p*32 + vkv, d-chunk vd0
  const int vkv = w * 8 + (l >> 3);
  const int vd0 = (l & 7) * 8;
  const int vkp = w * 4 + (l >> 4);
  const int dEff = vd0 + pb * 4;

  // K staging coords (source chunk pre-swizzled; involution key = row&7)
  const int srow = w * 8 + (l >> 3);
  const int schunk = (l & 7) ^ ((l >> 3) & 7);

  bf16x8 vcur[4], vnx[4];
#pragma unroll
  for (int p = 0; p < 4; ++p)
    vcur[p] = *(const bf16x8*)(vbase + (size_t)(p * 32 + vkv) * 3072 + vd0);

  for (int t = 0; t < nt; ++t) {
    // ---- issue K tile staging (overlaps V pack VALU) ----
    const u16* kt = kbase + (size_t)(t * 128) * 3072;
#pragma unroll
    for (int p = 0; p < 4; ++p)
      __builtin_amdgcn_global_load_lds(
          (const AS1 void*)(kt + (size_t)(p * 32 + srow) * 3072 + schunk * 8),
          (AS3 void*)((AS3 u16*)Ks + p * 2048 + w * 512), 16, 0, 0);

    // ---- pack + write V (pair lanes kv, kv^1 exchange halves) ----
#pragma unroll
    for (int p = 0; p < 4; ++p) {
      u32 dw0 = ((u32*)&vcur[p])[0], dw1 = ((u32*)&vcur[p])[1];
      u32 dw2 = ((u32*)&vcur[p])[2], dw3 = ((u32*)&vcur[p])[3];
      u32 s0 = (u32)__shfl_xor((int)(pb ? dw0 : dw2), 8, 64);
      u32 s1 = (u32)__shfl_xor((int)(pb ? dw1 : dw3), 8, 64);
      u32 md0 = pb ? dw2 : dw0, md1 = pb ? dw3 : dw1;
      u32 lo0 = pb ? s0 : md0, hi0 = pb ? md0 : s0;
      u32 lo1 = pb ? s1 : md1, hi1 = pb ? md1 : s1;
      int kp = p * 16 + vkp;
      Vt2[(dEff + 0) * 65 + kp] = (lo0 & 0xffffu) | (hi0 << 16);
      Vt2[(dEff + 1) * 65 + kp] = (lo0 >> 16) | (hi0 & 0xffff0000u);
      Vt2[(dEff + 2) * 65 + kp] = (lo1 & 0xffffu) | (hi1 << 16);
      Vt2[(dEff + 3) * 65 + kp] = (lo1 >> 16) | (hi1 & 0xffff0000u);
    }
    __syncthreads();  // drains K glds (vmcnt) + V writes (lgkm)

    // ---- prefetch next tile's V (drains at end-of-tile barrier) ----
    if (t + 1 < nt) {
      const u16* vt = vbase + (size_t)((t + 1) * 128) * 3072;
#pragma unroll
      for (int p = 0; p < 4; ++p)
        vnx[p] = *(const bf16x8*)(vt + (size_t)(p * 32 + vkv) * 3072 + vd0);
    }

    const bool diag = (t == nt - 1);
#pragma unroll
    for (int sub = 0; sub < 4; ++sub) {
      if (!(diag && sub > w)) {
        // ---- S[kv][q] = K . Q^T over d (4 slices) ----
        f32x16 sc = {};
#pragma unroll
        for (int c = 0; c < 4; ++c) {
          int r = sub * 32 + l31;
          int pc = (2 * c + hi) ^ (l31 & 7);
          bf16x8 kf = *(const bf16x8*)&Ks[r * 64 + pc * 8];
          sc = __builtin_amdgcn_mfma_f32_32x32x16_bf16(kf, qf[c], sc, 0, 0, 0);
        }
        // ---- scale (+ diagonal mask) ----
        float tv[16];
#pragma unroll
        for (int r = 0; r < 16; ++r) tv[r] = sc[r] * 0.125f;
        if (diag && sub == w) {
#pragma unroll
          for (int r = 0; r < 16; ++r) {
            int kvloc = (r & 3) + 8 * (r >> 2) + 4 * hi;
            if (kvloc > l31) tv[r] = -1e30f;
          }
        }
        // ---- in-lane max + partner combine ----
        float t0 = fmaxf(fmaxf(tv[0], tv[1]), fmaxf(tv[2], tv[3]));
        float t1 = fmaxf(fmaxf(tv[4], tv[5]), fmaxf(tv[6], tv[7]));
        float t2 = fmaxf(fmaxf(tv[8], tv[9]), fmaxf(tv[10], tv[11]));
        float t3 = fmaxf(fmaxf(tv[12], tv[13]), fmaxf(tv[14], tv[15]));
        float tmax = fmaxf(fmaxf(t0, t1), fmaxf(t2, t3));
        tmax = fmaxf(tmax, __shfl_xor(tmax, 32, 64));
        // ---- defer-max (T13, THR=8) ----
        if (!__all(tmax <= m_r + 8.0f)) {
          float nm = fmaxf(m_r, tmax);
          float alpha = __expf(m_r - nm);
          m_r = nm;
          l_r *= alpha;
#pragma unroll
          for (int r = 0; r < 16; ++r) { o0[r] *= alpha; o1[r] *= alpha; }
        }
        // ---- exp + row-sum ----
#pragma unroll
        for (int r = 0; r < 16; ++r) tv[r] = __expf(tv[r] - m_r);
        float s0_ = (tv[0] + tv[1]) + (tv[2] + tv[3]);
        float s1_ = (tv[4] + tv[5]) + (tv[6] + tv[7]);
        float s2_ = (tv[8] + tv[9]) + (tv[10] + tv[11]);
        float s3_ = (tv[12] + tv[13]) + (tv[14] + tv[15]);
        float psum = (s0_ + s1_) + (s2_ + s3_);
        psum += __shfl_xor(psum, 32, 64);
        l_r += psum;
        // ---- build P^T A-frags in-register, PV ----
#pragma unroll
        for (int s01 = 0; s01 < 2; ++s01) {
          u32 W0 = pk2(tv[8 * s01 + 0], tv[8 * s01 + 1]);
          u32 W1 = pk2(tv[8 * s01 + 2], tv[8 * s01 + 3]);
          u32 X0 = pk2(tv[8 * s01 + 4], tv[8 * s01 + 5]);
          u32 X1 = pk2(tv[8 * s01 + 6], tv[8 * s01 + 7]);
          u32 rW0 = (u32)__shfl_xor((int)W0, 32, 64);
          u32 rW1 = (u32)__shfl_xor((int)W1, 32, 64);
          u32 rX0 = (u32)__shfl_xor((int)X0, 32, 64);
          u32 rX1 = (u32)__shfl_xor((int)X1, 32, 64);
          u32x4 av;
          av[0] = hi ? rX0 : W0;
          av[1] = hi ? rX1 : W1;
          av[2] = hi ? X0 : rW0;
          av[3] = hi ? X1 : rW1;
          bf16x8 pa = *(bf16x8*)&av;
          int kpb = sub * 16 + s01 * 8 + hi * 4;
          u32x4 v0 = *(const u32x4*)&Vt2[(size_t)l31 * 65 + kpb];
          o0 = __builtin_amdgcn_mfma_f32_32x32x16_bf16(pa, *(bf16x8*)&v0, o0, 0, 0, 0);
          u32x4 v1 = *(const u32x4*)&Vt2[(size_t)(32 + l31) * 65 + kpb];
          o1 = __builtin_amdgcn_mfma_f32_32x32x16_bf16(pa, *(bf16x8*)&v1, o1, 0, 0, 0);
        }
      }
    }
    __syncthreads();
#pragma unroll
    for (int p = 0; p < 4; ++p) vcur[p] = vnx[p];
  }

  // ---- epilogue: gather 1/l per q-row, write O ----
#pragma unroll
  for (int r = 0; r < 16; ++r) {
    int qp = (r & 3) + 8 * (r >> 2) + 4 * hi;
    float ls = __shfl(l_r, qp, 64);
    float inv = __builtin_amdgcn_rcpf(ls);
    int trow = s * 1024 + qb * 128 + w * 32 + qp;
    attnout[(size_t)trow * 1024 + h * 64 + l31]      = f2bf(o0[r] * inv);
    attnout[(size_t)trow * 1024 + h * 64 + 32 + l31] = f2bf(o1[r] * inv);
  }
}

// ---------------- host launch ----------------
extern "C" void kernel_launch(void* const* d_in, const int* in_sizes, int n_in,
                              void* d_out, int out_size, void* d_ws, size_t ws_size,
                              hipStream_t stream) {
  const float* hs = (const float*)d_in[0];
  const float* Wq = (const float*)d_in[2];
  const float* bq = (const float*)d_in[3];
  const float* Wk = (const float*)d_in[4];
  const float* Wv = (const float*)d_in[5];
  const float* bv = (const float*)d_in[6];
  const float* Wo = (const float*)d_in[7];
  const float* bo = (const float*)d_in[8];

  char* ws = (char*)d_ws;
  u16* Xb    = (u16*)ws;
  u16* Wqkv  = (u16*)(ws + 16777216);
  u16* Wob   = (u16*)(ws + 23068672);
  float* bqk = (float*)(ws + 25165824);
  u16* qkv   = (u16*)(ws + 25178112);
  u16* attn  = (u16*)(ws + 75509760);

  cvt_all<<<2048, 256, 0, stream>>>(hs, Wq, Wk, Wv, Wo, Xb, Wqkv, Wob);
  build_bias<<<12, 256, 0, stream>>>(bq, bv, bqk);

  gemm_nt<0><<<1536, 256, 0, stream>>>(Xb, Wqkv, bqk, qkv, 8192, 3072, 1024, 24);

  attn_kernel<<<1024, 256, 0, stream>>>(qkv, attn);

  gemm_nt<1><<<512, 256, 0, stream>>>(attn, Wob, bo, d_out, 8192, 1024, 1024, 8);
}

// Round 6
// 264.005 us; speedup vs baseline: 1.2877x; 1.0872x over previous
//
#include <hip/hip_runtime.h>
#include <hip/hip_bf16.h>

// Fused attention block: QKV proj -> causal flash attention -> out proj.
// R5 = R4 resubmission (infra timeout, never benched) + bias fold into cvt.
// GEMMs: 256x256 8-phase schedule (T2 swizzle + T3/T4 counted-vmcnt + T5
// setprio). BK=64, 8 waves (2Mx4N), 512 thr, 128KB LDS, raw s_barrier,
// 1 half-tile staged/phase, vmcnt(4) once per K-tile.
// Attention: R3 swapped-QK^T 32x32 structure (verified).

typedef unsigned short u16;
typedef unsigned int   u32;
typedef __attribute__((ext_vector_type(8))) short bf16x8;
typedef __attribute__((ext_vector_type(4))) float f32x4;
typedef __attribute__((ext_vector_type(16))) float f32x16;
typedef __attribute__((ext_vector_type(4))) u32 u32x4;

#define AS1 __attribute__((address_space(1)))
#define AS3 __attribute__((address_space(3)))
#define FENCE asm volatile("" ::: "memory")
#define BAR() do { FENCE; __builtin_amdgcn_s_barrier(); FENCE; } while (0)

__device__ __forceinline__ u16 f2bf(float f) {
  u32 x = __float_as_uint(f);
  x += 0x7fffu + ((x >> 16) & 1u);
  return (u16)(x >> 16);
}
__device__ __forceinline__ u32 pk2(float a, float b) {
  return (u32)f2bf(a) | ((u32)f2bf(b) << 16);
}

// ---------- fused fp32->bf16 conversion + bias build ----------
__global__ __launch_bounds__(256) void cvt_all(const float* __restrict__ hs,
                                               const float* __restrict__ Wq,
                                               const float* __restrict__ Wk,
                                               const float* __restrict__ Wv,
                                               const float* __restrict__ Wo,
                                               const float* __restrict__ bq,
                                               const float* __restrict__ bv,
                                               u16* __restrict__ Xb,
                                               u16* __restrict__ Wqkv,
                                               u16* __restrict__ Wob,
                                               float* __restrict__ bias) {
  if (blockIdx.x == gridDim.x - 1) {
    for (int i = threadIdx.x; i < 3072; i += 256) {
      float v = 0.f;
      if (i < 1024) v = bq[i];
      else if (i >= 2048) v = bv[i - 2048];
      bias[i] = v;
    }
  }
  int i = blockIdx.x * 256 + threadIdx.x;
  const int stride = gridDim.x * 256;
  for (; i < 3145728; i += stride) {
    const float* src;
    u16* dst;
    int off;
    if (i < 2097152) {
      src = hs; dst = Xb; off = i;
    } else {
      int j = i - 2097152;
      int m = j >> 18;
      off = j & 262143;
      src = (m == 0) ? Wq : (m == 1) ? Wk : (m == 2) ? Wv : Wo;
      dst = (m < 3) ? (Wqkv + (size_t)m * 1048576) : Wob;
    }
    float4 v = ((const float4*)src)[off];
    u32 lo = (u32)f2bf(v.x) | ((u32)f2bf(v.y) << 16);
    u32 hi = (u32)f2bf(v.z) | ((u32)f2bf(v.w) << 16);
    ((u32*)dst)[off * 2]     = lo;
    ((u32*)dst)[off * 2 + 1] = hi;
  }
}

// ---------------- 256x256 8-phase bf16 NT GEMM ----------------------------
// C[m][n] = sum_k A[m][k]*B[n][k] + bias[n].  BK=64, 8 waves (2Mx4N).
__device__ __forceinline__ void quad16(f32x4 (&acc)[4][2],
                                       const bf16x8 (&af)[4][2],
                                       const bf16x8 (&bf)[2][2]) {
#pragma unroll
  for (int m = 0; m < 4; ++m)
#pragma unroll
    for (int n = 0; n < 2; ++n)
#pragma unroll
      for (int kk = 0; kk < 2; ++kk)
        acc[m][n] = __builtin_amdgcn_mfma_f32_16x16x32_bf16(
            af[m][kk], bf[n][kk], acc[m][n], 0, 0, 0);
}

template <int OUT_MODE>
__global__ __launch_bounds__(512, 2) void gemm8p(const u16* __restrict__ A,
                                                 const u16* __restrict__ Bw,
                                                 const float* __restrict__ bias,
                                                 void* __restrict__ C,
                                                 int M, int N, int K, int nbn) {
  // LDS: [buf][half][128 rows][64 cols] bf16, chunk-swizzled (chunk ^= row&7)
  __shared__ __align__(16) u16 sA[2][2][128 * 64];
  __shared__ __align__(16) u16 sB[2][2][128 * 64];

  const int cpx = gridDim.x >> 3;
  const int swz = ((int)blockIdx.x & 7) * cpx + ((int)blockIdx.x >> 3);
  const int bn = swz % nbn, bm = swz / nbn;
  const int tid = threadIdx.x;
  const int l = tid & 63, w = tid >> 6;
  const int l15 = l & 15, lg = (l >> 4) & 3;
  const int wr = w >> 2, wc = w & 3;   // wave grid 2(M) x 4(N)
  const int bh = wc >> 1;              // which B half this wave reads

  const u16* Ab = A + (size_t)(bm * 256) * K;
  const u16* Bb = Bw + (size_t)(bn * 256) * K;

  // staging coords: slot = j*512 + w*64 + l -> row=slot>>3, chunk=l&7
  const int sr = w * 8 + (l >> 3);
  const int sch = (l & 7) ^ ((l >> 3) & 7);   // pre-swizzled source chunk
  const int sldso = w * 64 * 8;               // u16 offset of wave dest (j=0)

  auto STAGE = [&](const u16* Xb, u16* lds, int hf, int kt) {
    const u16* src = Xb + (size_t)(hf * 128) * K + kt * 64;
#pragma unroll
    for (int j = 0; j < 2; ++j)
      __builtin_amdgcn_global_load_lds(
          (const AS1 void*)(src + (size_t)(j * 64 + sr) * K + sch * 8),
          (AS3 void*)((AS3 u16*)lds + j * 512 * 8 + sldso), 16, 0, 0);
  };
  auto LDA = [&](const u16* Ah, int mh, int m, int kk) -> bf16x8 {
    int row = mh * 64 + m * 16 + l15;
    int ch = (kk * 4 + lg) ^ (l15 & 7);
    return *(const bf16x8*)&Ah[row * 64 + ch * 8];
  };
  auto LDB = [&](const u16* Bh, int nh, int n, int kk) -> bf16x8 {
    int row = (wc & 1) * 64 + nh * 32 + n * 16 + l15;
    int ch = (kk * 4 + lg) ^ (l15 & 7);
    return *(const bf16x8*)&Bh[row * 64 + ch * 8];
  };

  f32x4 acc[2][2][4][2] = {};  // [mh][nh][m][n]
  const int NT = K >> 6;

  // ---- prologue: kt0 fully + kt1's B halves; keep 4 newest in flight ----
  STAGE(Ab, &sA[0][0][0], 0, 0);
  STAGE(Ab, &sA[0][1][0], 1, 0);
  STAGE(Bb, &sB[0][0][0], 0, 0);
  STAGE(Bb, &sB[0][1][0], 1, 0);
  STAGE(Bb, &sB[1][0][0], 0, 1);
  STAGE(Bb, &sB[1][1][0], 1, 1);
  asm volatile("s_waitcnt vmcnt(4)" ::: "memory");
  BAR();

  for (int kt = 0; kt < NT; ++kt) {
    const int p = kt & 1;
    const u16* Ah = &sA[p][wr][0];
    const u16* Bh = &sB[p][bh][0];
    bf16x8 af0[4][2], af1[4][2], bf0[2][2], bf1[2][2];

    // ---- phase 0 : quad (0,0); stage A0 of kt+1 ----
#pragma unroll
    for (int m = 0; m < 4; ++m)
#pragma unroll
      for (int kk = 0; kk < 2; ++kk) af0[m][kk] = LDA(Ah, 0, m, kk);
#pragma unroll
    for (int n = 0; n < 2; ++n)
#pragma unroll
      for (int kk = 0; kk < 2; ++kk) bf0[n][kk] = LDB(Bh, 0, n, kk);
    if (kt + 1 < NT) STAGE(Ab, &sA[p ^ 1][0][0], 0, kt + 1);
    BAR();
    __builtin_amdgcn_s_setprio(1);
    quad16(acc[0][0], af0, bf0);
    __builtin_amdgcn_s_setprio(0);
    BAR();

    // ---- phase 1 : quad (0,1); stage A1 of kt+1 ----
#pragma unroll
    for (int n = 0; n < 2; ++n)
#pragma unroll
      for (int kk = 0; kk < 2; ++kk) bf1[n][kk] = LDB(Bh, 1, n, kk);
    if (kt + 1 < NT) STAGE(Ab, &sA[p ^ 1][1][0], 1, kt + 1);
    BAR();
    __builtin_amdgcn_s_setprio(1);
    quad16(acc[0][1], af0, bf1);
    __builtin_amdgcn_s_setprio(0);
    BAR();

    // ---- phase 2 : quad (1,1); stage B0 of kt+2 (B region dead after ph1) --
#pragma unroll
    for (int m = 0; m < 4; ++m)
#pragma unroll
      for (int kk = 0; kk < 2; ++kk) af1[m][kk] = LDA(Ah, 1, m, kk);
    if (kt + 2 < NT) STAGE(Bb, &sB[p][0][0], 0, kt + 2);
    BAR();
    __builtin_amdgcn_s_setprio(1);
    quad16(acc[1][1], af1, bf1);
    __builtin_amdgcn_s_setprio(0);
    BAR();

    // ---- phase 3 : quad (1,0); stage B1 of kt+2; counted vmcnt ----
    if (kt + 2 < NT) STAGE(Bb, &sB[p][1][0], 1, kt + 2);
    BAR();
    __builtin_amdgcn_s_setprio(1);
    quad16(acc[1][0], af1, bf0);
    __builtin_amdgcn_s_setprio(0);
    if (kt >= NT - 2) asm volatile("s_waitcnt vmcnt(0)" ::: "memory");
    else              asm volatile("s_waitcnt vmcnt(4)" ::: "memory");
    BAR();
  }

  // ---- epilogue ----
#pragma unroll
  for (int mh = 0; mh < 2; ++mh)
#pragma unroll
    for (int m = 0; m < 4; ++m)
#pragma unroll
      for (int i = 0; i < 4; ++i) {
        int row = bm * 256 + wr * 128 + mh * 64 + m * 16 + lg * 4 + i;
#pragma unroll
        for (int nh = 0; nh < 2; ++nh)
#pragma unroll
          for (int n = 0; n < 2; ++n) {
            int col = bn * 256 + wc * 64 + nh * 32 + n * 16 + l15;
            float v = acc[mh][nh][m][n][i] + bias[col];
            if (OUT_MODE == 0)
              ((u16*)C)[(size_t)row * N + col] = f2bf(v);
            else
              ((float*)C)[(size_t)row * N + col] = v;
          }
      }
}

// ---------------- flash attention: swapped-QK^T 32x32 structure -----------
__global__ __launch_bounds__(256, 4) void attn_kernel(const u16* __restrict__ qkv,
                                                      u16* __restrict__ attnout) {
  const int bid = (blockIdx.x & 7) * 128 + (blockIdx.x >> 3);  // XCD: 1 seq/XCD
  const int qb = 7 - (bid & 7);                                // longest first
  const int h = (bid >> 3) & 15;
  const int s = bid >> 7;
  const int tid = threadIdx.x;
  const int l = tid & 63, w = tid >> 6;
  const int l31 = l & 31;
  const int hi = l >> 5;
  const int pb = (l >> 3) & 1;

  __shared__ __align__(16) u16 Ks[128 * 64];   // XOR-swizzled [kv][d]
  __shared__ __align__(16) u32 Vt2[64 * 65];   // [d][kvpair], pad 65

  const u16* kbase = qkv + (size_t)(s * 1024) * 3072 + 1024 + h * 64;
  const u16* vbase = qkv + (size_t)(s * 1024) * 3072 + 2048 + h * 64;

  bf16x8 qf[4];
  {
    const u16* qptr = qkv + (size_t)(s * 1024 + qb * 128 + w * 32 + l31) * 3072 + h * 64 + hi * 8;
#pragma unroll
    for (int c = 0; c < 4; ++c) qf[c] = *(const bf16x8*)(qptr + c * 16);
  }

  float m_r = -1e30f, l_r = 0.f;
  f32x16 o0 = {}, o1 = {};

  const int nt = qb + 1;

  const int vkv = w * 8 + (l >> 3);
  const int vd0 = (l & 7) * 8;
  const int vkp = w * 4 + (l >> 4);
  const int dEff = vd0 + pb * 4;

  const int srow = w * 8 + (l >> 3);
  const int schunk = (l & 7) ^ ((l >> 3) & 7);

  bf16x8 vcur[4], vnx[4];
#pragma unroll
  for (int p = 0; p < 4; ++p)
    vcur[p] = *(const bf16x8*)(vbase + (size_t)(p * 32 + vkv) * 3072 + vd0);

  for (int t = 0; t < nt; ++t) {
    const u16* kt = kbase + (size_t)(t * 128) * 3072;
#pragma unroll
    for (int p = 0; p < 4; ++p)
      __builtin_amdgcn_global_load_lds(
          (const AS1 void*)(kt + (size_t)(p * 32 + srow) * 3072 + schunk * 8),
          (AS3 void*)((AS3 u16*)Ks + p * 2048 + w * 512), 16, 0, 0);

#pragma unroll
    for (int p = 0; p < 4; ++p) {
      u32 dw0 = ((u32*)&vcur[p])[0], dw1 = ((u32*)&vcur[p])[1];
      u32 dw2 = ((u32*)&vcur[p])[2], dw3 = ((u32*)&vcur[p])[3];
      u32 s0 = (u32)__shfl_xor((int)(pb ? dw0 : dw2), 8, 64);
      u32 s1 = (u32)__shfl_xor((int)(pb ? dw1 : dw3), 8, 64);
      u32 md0 = pb ? dw2 : dw0, md1 = pb ? dw3 : dw1;
      u32 lo0 = pb ? s0 : md0, hi0 = pb ? md0 : s0;
      u32 lo1 = pb ? s1 : md1, hi1 = pb ? md1 : s1;
      int kp = p * 16 + vkp;
      Vt2[(dEff + 0) * 65 + kp] = (lo0 & 0xffffu) | (hi0 << 16);
      Vt2[(dEff + 1) * 65 + kp] = (lo0 >> 16) | (hi0 & 0xffff0000u);
      Vt2[(dEff + 2) * 65 + kp] = (lo1 & 0xffffu) | (hi1 << 16);
      Vt2[(dEff + 3) * 65 + kp] = (lo1 >> 16) | (hi1 & 0xffff0000u);
    }
    __syncthreads();

    if (t + 1 < nt) {
      const u16* vt = vbase + (size_t)((t + 1) * 128) * 3072;
#pragma unroll
      for (int p = 0; p < 4; ++p)
        vnx[p] = *(const bf16x8*)(vt + (size_t)(p * 32 + vkv) * 3072 + vd0);
    }

    const bool diag = (t == nt - 1);
#pragma unroll
    for (int sub = 0; sub < 4; ++sub) {
      if (!(diag && sub > w)) {
        f32x16 sc = {};
#pragma unroll
        for (int c = 0; c < 4; ++c) {
          int r = sub * 32 + l31;
          int pc = (2 * c + hi) ^ (l31 & 7);
          bf16x8 kf = *(const bf16x8*)&Ks[r * 64 + pc * 8];
          sc = __builtin_amdgcn_mfma_f32_32x32x16_bf16(kf, qf[c], sc, 0, 0, 0);
        }
        float tv[16];
#pragma unroll
        for (int r = 0; r < 16; ++r) tv[r] = sc[r] * 0.125f;
        if (diag && sub == w) {
#pragma unroll
          for (int r = 0; r < 16; ++r) {
            int kvloc = (r & 3) + 8 * (r >> 2) + 4 * hi;
            if (kvloc > l31) tv[r] = -1e30f;
          }
        }
        float t0 = fmaxf(fmaxf(tv[0], tv[1]), fmaxf(tv[2], tv[3]));
        float t1 = fmaxf(fmaxf(tv[4], tv[5]), fmaxf(tv[6], tv[7]));
        float t2 = fmaxf(fmaxf(tv[8], tv[9]), fmaxf(tv[10], tv[11]));
        float t3 = fmaxf(fmaxf(tv[12], tv[13]), fmaxf(tv[14], tv[15]));
        float tmax = fmaxf(fmaxf(t0, t1), fmaxf(t2, t3));
        tmax = fmaxf(tmax, __shfl_xor(tmax, 32, 64));
        if (!__all(tmax <= m_r + 8.0f)) {
          float nm = fmaxf(m_r, tmax);
          float alpha = __expf(m_r - nm);
          m_r = nm;
          l_r *= alpha;
#pragma unroll
          for (int r = 0; r < 16; ++r) { o0[r] *= alpha; o1[r] *= alpha; }
        }
#pragma unroll
        for (int r = 0; r < 16; ++r) tv[r] = __expf(tv[r] - m_r);
        float s0_ = (tv[0] + tv[1]) + (tv[2] + tv[3]);
        float s1_ = (tv[4] + tv[5]) + (tv[6] + tv[7]);
        float s2_ = (tv[8] + tv[9]) + (tv[10] + tv[11]);
        float s3_ = (tv[12] + tv[13]) + (tv[14] + tv[15]);
        float psum = (s0_ + s1_) + (s2_ + s3_);
        psum += __shfl_xor(psum, 32, 64);
        l_r += psum;
#pragma unroll
        for (int s01 = 0; s01 < 2; ++s01) {
          u32 W0 = pk2(tv[8 * s01 + 0], tv[8 * s01 + 1]);
          u32 W1 = pk2(tv[8 * s01 + 2], tv[8 * s01 + 3]);
          u32 X0 = pk2(tv[8 * s01 + 4], tv[8 * s01 + 5]);
          u32 X1 = pk2(tv[8 * s01 + 6], tv[8 * s01 + 7]);
          u32 rW0 = (u32)__shfl_xor((int)W0, 32, 64);
          u32 rW1 = (u32)__shfl_xor((int)W1, 32, 64);
          u32 rX0 = (u32)__shfl_xor((int)X0, 32, 64);
          u32 rX1 = (u32)__shfl_xor((int)X1, 32, 64);
          u32x4 av;
          av[0] = hi ? rX0 : W0;
          av[1] = hi ? rX1 : W1;
          av[2] = hi ? X0 : rW0;
          av[3] = hi ? X1 : rW1;
          bf16x8 pa = *(bf16x8*)&av;
          int kpb = sub * 16 + s01 * 8 + hi * 4;
          u32x4 v0 = *(const u32x4*)&Vt2[(size_t)l31 * 65 + kpb];
          o0 = __builtin_amdgcn_mfma_f32_32x32x16_bf16(pa, *(bf16x8*)&v0, o0, 0, 0, 0);
          u32x4 v1 = *(const u32x4*)&Vt2[(size_t)(32 + l31) * 65 + kpb];
          o1 = __builtin_amdgcn_mfma_f32_32x32x16_bf16(pa, *(bf16x8*)&v1, o1, 0, 0, 0);
        }
      }
    }
    __syncthreads();
#pragma unroll
    for (int p = 0; p < 4; ++p) vcur[p] = vnx[p];
  }

#pragma unroll
  for (int r = 0; r < 16; ++r) {
    int qp = (r & 3) + 8 * (r >> 2) + 4 * hi;
    float ls = __shfl(l_r, qp, 64);
    float inv = __builtin_amdgcn_rcpf(ls);
    int trow = s * 1024 + qb * 128 + w * 32 + qp;
    attnout[(size_t)trow * 1024 + h * 64 + l31]      = f2bf(o0[r] * inv);
    attnout[(size_t)trow * 1024 + h * 64 + 32 + l31] = f2bf(o1[r] * inv);
  }
}

// ---------------- host launch ----------------
extern "C" void kernel_launch(void* const* d_in, const int* in_sizes, int n_in,
                              void* d_out, int out_size, void* d_ws, size_t ws_size,
                              hipStream_t stream) {
  const float* hs = (const float*)d_in[0];
  const float* Wq = (const float*)d_in[2];
  const float* bq = (const float*)d_in[3];
  const float* Wk = (const float*)d_in[4];
  const float* Wv = (const float*)d_in[5];
  const float* bv = (const float*)d_in[6];
  const float* Wo = (const float*)d_in[7];
  const float* bo = (const float*)d_in[8];

  char* ws = (char*)d_ws;
  u16* Xb    = (u16*)ws;
  u16* Wqkv  = (u16*)(ws + 16777216);
  u16* Wob   = (u16*)(ws + 23068672);
  float* bqk = (float*)(ws + 25165824);
  u16* qkv   = (u16*)(ws + 25178112);
  u16* attn  = (u16*)(ws + 75509760);

  cvt_all<<<2048, 256, 0, stream>>>(hs, Wq, Wk, Wv, Wo, bq, bv, Xb, Wqkv, Wob, bqk);

  gemm8p<0><<<384, 512, 0, stream>>>(Xb, Wqkv, bqk, qkv, 8192, 3072, 1024, 12);

  attn_kernel<<<1024, 256, 0, stream>>>(qkv, attn);

  gemm8p<1><<<128, 512, 0, stream>>>(attn, Wob, bo, d_out, 8192, 1024, 1024, 4);
}

// Round 9
// 252.422 us; speedup vs baseline: 1.3468x; 1.0459x over previous
//
#include <hip/hip_runtime.h>
#include <hip/hip_bf16.h>

// Fused attention block: QKV proj -> causal flash attention -> out proj.
// R8 = R7 resubmission (infra timeout, never benched).
// GEMM 128x256, 2 phases/K-tile, A 2-buf + B 3-buf (offset lambdas, no
// static-init LDS pointer arrays), counted vmcnt(4), coalesced LDS-repack
// epilogue with fused bias. Attention: R3 swapped-QK^T 32x32 (verified).

typedef unsigned short u16;
typedef unsigned int   u32;
typedef __attribute__((ext_vector_type(8))) short bf16x8;
typedef __attribute__((ext_vector_type(4))) float f32x4;
typedef __attribute__((ext_vector_type(16))) float f32x16;
typedef __attribute__((ext_vector_type(4))) u32 u32x4;
typedef __attribute__((ext_vector_type(2))) u32 u32x2;

#define AS1 __attribute__((address_space(1)))
#define AS3 __attribute__((address_space(3)))
#define FENCE asm volatile("" ::: "memory")
#define BAR() do { FENCE; __builtin_amdgcn_s_barrier(); FENCE; } while (0)

__device__ __forceinline__ u16 f2bf(float f) {
  u32 x = __float_as_uint(f);
  x += 0x7fffu + ((x >> 16) & 1u);
  return (u16)(x >> 16);
}
__device__ __forceinline__ u32 pk2(float a, float b) {
  return (u32)f2bf(a) | ((u32)f2bf(b) << 16);
}

// ---------- fused fp32->bf16 conversion + bias build ----------
__global__ __launch_bounds__(256) void cvt_all(const float* __restrict__ hs,
                                               const float* __restrict__ Wq,
                                               const float* __restrict__ Wk,
                                               const float* __restrict__ Wv,
                                               const float* __restrict__ Wo,
                                               const float* __restrict__ bq,
                                               const float* __restrict__ bv,
                                               u16* __restrict__ Xb,
                                               u16* __restrict__ Wqkv,
                                               u16* __restrict__ Wob,
                                               float* __restrict__ bias) {
  if (blockIdx.x == gridDim.x - 1) {
    for (int i = threadIdx.x; i < 3072; i += 256) {
      float v = 0.f;
      if (i < 1024) v = bq[i];
      else if (i >= 2048) v = bv[i - 2048];
      bias[i] = v;
    }
  }
  int i = blockIdx.x * 256 + threadIdx.x;
  const int stride = gridDim.x * 256;
  for (; i < 3145728; i += stride) {
    const float* src;
    u16* dst;
    int off;
    if (i < 2097152) {
      src = hs; dst = Xb; off = i;
    } else {
      int j = i - 2097152;
      int m = j >> 18;
      off = j & 262143;
      src = (m == 0) ? Wq : (m == 1) ? Wk : (m == 2) ? Wv : Wo;
      dst = (m < 3) ? (Wqkv + (size_t)m * 1048576) : Wob;
    }
    float4 v = ((const float4*)src)[off];
    u32 lo = (u32)f2bf(v.x) | ((u32)f2bf(v.y) << 16);
    u32 hi = (u32)f2bf(v.z) | ((u32)f2bf(v.w) << 16);
    ((u32*)dst)[off * 2]     = lo;
    ((u32*)dst)[off * 2 + 1] = hi;
  }
}

// ---------------- 128x256 2-phase bf16 NT GEMM ----------------------------
// C[m][n] = sum_k A[m][k]*B[n][k] + bias[n].  BK=64, 8 waves (2Mx4N),
// wave tile 64x64. A 2-buf (16KB ea), B 3-buf (32KB ea) -> 128KB LDS.
template <int OUT_MODE>
__global__ __launch_bounds__(512, 2) void gemm8p(const u16* __restrict__ A,
                                                 const u16* __restrict__ Bw,
                                                 const float* __restrict__ bias,
                                                 void* __restrict__ C,
                                                 int M, int N, int K, int nbn) {
  __shared__ __align__(16) unsigned char smem[131072];
  auto bufA = [&](int p) -> u16* { return (u16*)(smem + (size_t)p * 16384); };
  auto bufB = [&](int p) -> u16* { return (u16*)(smem + 32768 + (size_t)p * 32768); };

  const int cpx = gridDim.x >> 3;
  const int swz = ((int)blockIdx.x & 7) * cpx + ((int)blockIdx.x >> 3);
  const int bn = swz % nbn, bm = swz / nbn;
  const int tid = threadIdx.x;
  const int l = tid & 63, w = tid >> 6;
  const int l15 = l & 15, lg = (l >> 4) & 3;
  const int wr = w >> 2, wc = w & 3;   // wave grid 2(M) x 4(N)

  const u16* Ab = A + (size_t)(bm * 128) * K;
  const u16* Bb = Bw + (size_t)(bn * 256) * K;

  // staging coords: unit = 128 rows x 64 cols; slot row = j*64 + w*8 + (l>>3)
  const int sr = w * 8 + (l >> 3);
  const int sch = (l & 7) ^ ((l >> 3) & 7);   // pre-swizzled source chunk
  const int sldso = w * 64 * 8;               // u16 offset of wave dest (j=0)

  auto STG = [&](const u16* src, u16* lds) {   // one 128x64 unit (2 loads/thr)
#pragma unroll
    for (int j = 0; j < 2; ++j)
      __builtin_amdgcn_global_load_lds(
          (const AS1 void*)(src + (size_t)(j * 64 + sr) * K + sch * 8),
          (AS3 void*)((AS3 u16*)lds + j * 4096 + sldso), 16, 0, 0);
  };
  auto LDA = [&](const u16* Ah, int m, int kk) -> bf16x8 {
    int row = wr * 64 + m * 16 + l15;
    int ch = (kk * 4 + lg) ^ (l15 & 7);
    return *(const bf16x8*)&Ah[row * 64 + ch * 8];
  };
  auto LDB = [&](const u16* Bh, int n, int kk) -> bf16x8 {
    int row = wc * 64 + n * 16 + l15;
    int ch = (kk * 4 + lg) ^ (l15 & 7);
    return *(const bf16x8*)&Bh[row * 64 + ch * 8];
  };

  f32x4 acc[4][4] = {};  // [m][n], wave tile 64x64
  const int NT = K >> 6;

  // ---- prologue: A(0), B(0) + B(1); leave B(1) (4 loads) in flight ----
  STG(Ab, bufA(0));
  STG(Bb, bufB(0));
  STG(Bb + (size_t)128 * K, bufB(0) + 8192);
  STG(Bb + 64, bufB(1));
  STG(Bb + (size_t)128 * K + 64, bufB(1) + 8192);
  asm volatile("s_waitcnt vmcnt(4)" ::: "memory");
  BAR();

  int pa = 0, pb = 0;
  for (int kt = 0; kt < NT; ++kt) {
    const u16* Ah = bufA(pa);
    const u16* Bh = bufB(pb);
    const int pa1 = pa ^ 1;
    int pb2 = pb + 2; if (pb2 >= 3) pb2 -= 3;   // (kt+2)%3
    bf16x8 af[4][2], bf0[2][2], bf1[2][2];

    // ---- phase 0 : n-half 0; stage A(kt+1), B-unit0(kt+2) ----
#pragma unroll
    for (int m = 0; m < 4; ++m)
#pragma unroll
      for (int kk = 0; kk < 2; ++kk) af[m][kk] = LDA(Ah, m, kk);
#pragma unroll
    for (int n = 0; n < 2; ++n)
#pragma unroll
      for (int kk = 0; kk < 2; ++kk) bf0[n][kk] = LDB(Bh, n, kk);
    if (kt + 1 < NT) STG(Ab + (kt + 1) * 64, bufA(pa1));
    if (kt + 2 < NT) STG(Bb + (kt + 2) * 64, bufB(pb2));
    BAR();
    __builtin_amdgcn_s_setprio(1);
#pragma unroll
    for (int m = 0; m < 4; ++m)
#pragma unroll
      for (int n = 0; n < 2; ++n)
#pragma unroll
        for (int kk = 0; kk < 2; ++kk)
          acc[m][n] = __builtin_amdgcn_mfma_f32_16x16x32_bf16(
              af[m][kk], bf0[n][kk], acc[m][n], 0, 0, 0);
    __builtin_amdgcn_s_setprio(0);
    BAR();

    // ---- phase 1 : n-half 1; stage B-unit1(kt+2); counted vmcnt ----
#pragma unroll
    for (int n = 0; n < 2; ++n)
#pragma unroll
      for (int kk = 0; kk < 2; ++kk) bf1[n][kk] = LDB(Bh, n + 2, kk);
    if (kt + 2 < NT) STG(Bb + (size_t)128 * K + (kt + 2) * 64, bufB(pb2) + 8192);
    BAR();
    __builtin_amdgcn_s_setprio(1);
#pragma unroll
    for (int m = 0; m < 4; ++m)
#pragma unroll
      for (int n = 0; n < 2; ++n)
#pragma unroll
        for (int kk = 0; kk < 2; ++kk)
          acc[m][n + 2] = __builtin_amdgcn_mfma_f32_16x16x32_bf16(
              af[m][kk], bf1[n][kk], acc[m][n + 2], 0, 0, 0);
    __builtin_amdgcn_s_setprio(0);
    // retire B(kt+1)+A(kt+1) (6 oldest of 10); keep B(kt+2) (4) in flight
    if (kt < NT - 2) asm volatile("s_waitcnt vmcnt(4)" ::: "memory");
    else             asm volatile("s_waitcnt vmcnt(0)" ::: "memory");
    BAR();
    pa = pa1;
    pb = (pb + 1 == 3) ? 0 : pb + 1;
  }

  // ---- epilogue: repack through LDS -> coalesced stores, fused bias ----
  float* eb = (float*)smem;  // [128][132] f32, 67.6KB
  const int mychunk = wc >> 1;
#pragma unroll
  for (int ch = 0; ch < 2; ++ch) {
    __syncthreads();
    if (mychunk == ch) {
#pragma unroll
      for (int m = 0; m < 4; ++m)
#pragma unroll
        for (int n = 0; n < 4; ++n)
#pragma unroll
          for (int i = 0; i < 4; ++i)
            eb[(wr * 64 + m * 16 + lg * 4 + i) * 132 + (wc & 1) * 64 + n * 16 + l15] =
                acc[m][n][i];
    }
    __syncthreads();
#pragma unroll
    for (int ps = 0; ps < 8; ++ps) {
      int idx = (ps * 512 + tid) * 4;
      int row = idx >> 7, col = idx & 127;
      f32x4 v = *(const f32x4*)&eb[row * 132 + col];
      int colg = bn * 256 + ch * 128 + col;
      f32x4 b = *(const f32x4*)&bias[colg];
      size_t go = (size_t)(bm * 128 + row) * N + colg;
      if (OUT_MODE == 0) {
        u32x2 o;
        o[0] = pk2(v[0] + b[0], v[1] + b[1]);
        o[1] = pk2(v[2] + b[2], v[3] + b[3]);
        *(u32x2*)((u16*)C + go) = o;
      } else {
        f32x4 o = {v[0] + b[0], v[1] + b[1], v[2] + b[2], v[3] + b[3]};
        *(f32x4*)((float*)C + go) = o;
      }
    }
  }
}

// ---------------- flash attention: swapped-QK^T 32x32 structure -----------
__global__ __launch_bounds__(256, 4) void attn_kernel(const u16* __restrict__ qkv,
                                                      u16* __restrict__ attnout) {
  const int bid = (blockIdx.x & 7) * 128 + (blockIdx.x >> 3);  // XCD: 1 seq/XCD
  const int qb = 7 - (bid & 7);                                // longest first
  const int h = (bid >> 3) & 15;
  const int s = bid >> 7;
  const int tid = threadIdx.x;
  const int l = tid & 63, w = tid >> 6;
  const int l31 = l & 31;
  const int hi = l >> 5;
  const int pb = (l >> 3) & 1;

  __shared__ __align__(16) u16 Ks[128 * 64];   // XOR-swizzled [kv][d]
  __shared__ __align__(16) u32 Vt2[64 * 65];   // [d][kvpair], pad 65

  const u16* kbase = qkv + (size_t)(s * 1024) * 3072 + 1024 + h * 64;
  const u16* vbase = qkv + (size_t)(s * 1024) * 3072 + 2048 + h * 64;

  bf16x8 qf[4];
  {
    const u16* qptr = qkv + (size_t)(s * 1024 + qb * 128 + w * 32 + l31) * 3072 + h * 64 + hi * 8;
#pragma unroll
    for (int c = 0; c < 4; ++c) qf[c] = *(const bf16x8*)(qptr + c * 16);
  }

  float m_r = -1e30f, l_r = 0.f;
  f32x16 o0 = {}, o1 = {};

  const int nt = qb + 1;

  const int vkv = w * 8 + (l >> 3);
  const int vd0 = (l & 7) * 8;
  const int vkp = w * 4 + (l >> 4);
  const int dEff = vd0 + pb * 4;

  const int srow = w * 8 + (l >> 3);
  const int schunk = (l & 7) ^ ((l >> 3) & 7);

  bf16x8 vcur[4], vnx[4];
#pragma unroll
  for (int p = 0; p < 4; ++p)
    vcur[p] = *(const bf16x8*)(vbase + (size_t)(p * 32 + vkv) * 3072 + vd0);

  for (int t = 0; t < nt; ++t) {
    const u16* kt = kbase + (size_t)(t * 128) * 3072;
#pragma unroll
    for (int p = 0; p < 4; ++p)
      __builtin_amdgcn_global_load_lds(
          (const AS1 void*)(kt + (size_t)(p * 32 + srow) * 3072 + schunk * 8),
          (AS3 void*)((AS3 u16*)Ks + p * 2048 + w * 512), 16, 0, 0);

#pragma unroll
    for (int p = 0; p < 4; ++p) {
      u32 dw0 = ((u32*)&vcur[p])[0], dw1 = ((u32*)&vcur[p])[1];
      u32 dw2 = ((u32*)&vcur[p])[2], dw3 = ((u32*)&vcur[p])[3];
      u32 s0 = (u32)__shfl_xor((int)(pb ? dw0 : dw2), 8, 64);
      u32 s1 = (u32)__shfl_xor((int)(pb ? dw1 : dw3), 8, 64);
      u32 md0 = pb ? dw2 : dw0, md1 = pb ? dw3 : dw1;
      u32 lo0 = pb ? s0 : md0, hi0 = pb ? md0 : s0;
      u32 lo1 = pb ? s1 : md1, hi1 = pb ? md1 : s1;
      int kp = p * 16 + vkp;
      Vt2[(dEff + 0) * 65 + kp] = (lo0 & 0xffffu) | (hi0 << 16);
      Vt2[(dEff + 1) * 65 + kp] = (lo0 >> 16) | (hi0 & 0xffff0000u);
      Vt2[(dEff + 2) * 65 + kp] = (lo1 & 0xffffu) | (hi1 << 16);
      Vt2[(dEff + 3) * 65 + kp] = (lo1 >> 16) | (hi1 & 0xffff0000u);
    }
    __syncthreads();

    if (t + 1 < nt) {
      const u16* vt = vbase + (size_t)((t + 1) * 128) * 3072;
#pragma unroll
      for (int p = 0; p < 4; ++p)
        vnx[p] = *(const bf16x8*)(vt + (size_t)(p * 32 + vkv) * 3072 + vd0);
    }

    const bool diag = (t == nt - 1);
#pragma unroll
    for (int sub = 0; sub < 4; ++sub) {
      if (!(diag && sub > w)) {
        f32x16 sc = {};
#pragma unroll
        for (int c = 0; c < 4; ++c) {
          int r = sub * 32 + l31;
          int pc = (2 * c + hi) ^ (l31 & 7);
          bf16x8 kf = *(const bf16x8*)&Ks[r * 64 + pc * 8];
          sc = __builtin_amdgcn_mfma_f32_32x32x16_bf16(kf, qf[c], sc, 0, 0, 0);
        }
        float tv[16];
#pragma unroll
        for (int r = 0; r < 16; ++r) tv[r] = sc[r] * 0.125f;
        if (diag && sub == w) {
#pragma unroll
          for (int r = 0; r < 16; ++r) {
            int kvloc = (r & 3) + 8 * (r >> 2) + 4 * hi;
            if (kvloc > l31) tv[r] = -1e30f;
          }
        }
        float t0 = fmaxf(fmaxf(tv[0], tv[1]), fmaxf(tv[2], tv[3]));
        float t1 = fmaxf(fmaxf(tv[4], tv[5]), fmaxf(tv[6], tv[7]));
        float t2 = fmaxf(fmaxf(tv[8], tv[9]), fmaxf(tv[10], tv[11]));
        float t3 = fmaxf(fmaxf(tv[12], tv[13]), fmaxf(tv[14], tv[15]));
        float tmax = fmaxf(fmaxf(t0, t1), fmaxf(t2, t3));
        tmax = fmaxf(tmax, __shfl_xor(tmax, 32, 64));
        if (!__all(tmax <= m_r + 8.0f)) {
          float nm = fmaxf(m_r, tmax);
          float alpha = __expf(m_r - nm);
          m_r = nm;
          l_r *= alpha;
#pragma unroll
          for (int r = 0; r < 16; ++r) { o0[r] *= alpha; o1[r] *= alpha; }
        }
#pragma unroll
        for (int r = 0; r < 16; ++r) tv[r] = __expf(tv[r] - m_r);
        float s0_ = (tv[0] + tv[1]) + (tv[2] + tv[3]);
        float s1_ = (tv[4] + tv[5]) + (tv[6] + tv[7]);
        float s2_ = (tv[8] + tv[9]) + (tv[10] + tv[11]);
        float s3_ = (tv[12] + tv[13]) + (tv[14] + tv[15]);
        float psum = (s0_ + s1_) + (s2_ + s3_);
        psum += __shfl_xor(psum, 32, 64);
        l_r += psum;
#pragma unroll
        for (int s01 = 0; s01 < 2; ++s01) {
          u32 W0 = pk2(tv[8 * s01 + 0], tv[8 * s01 + 1]);
          u32 W1 = pk2(tv[8 * s01 + 2], tv[8 * s01 + 3]);
          u32 X0 = pk2(tv[8 * s01 + 4], tv[8 * s01 + 5]);
          u32 X1 = pk2(tv[8 * s01 + 6], tv[8 * s01 + 7]);
          u32 rW0 = (u32)__shfl_xor((int)W0, 32, 64);
          u32 rW1 = (u32)__shfl_xor((int)W1, 32, 64);
          u32 rX0 = (u32)__shfl_xor((int)X0, 32, 64);
          u32 rX1 = (u32)__shfl_xor((int)X1, 32, 64);
          u32x4 av;
          av[0] = hi ? rX0 : W0;
          av[1] = hi ? rX1 : W1;
          av[2] = hi ? X0 : rW0;
          av[3] = hi ? X1 : rW1;
          bf16x8 pa = *(bf16x8*)&av;
          int kpb = sub * 16 + s01 * 8 + hi * 4;
          u32x4 v0 = *(const u32x4*)&Vt2[(size_t)l31 * 65 + kpb];
          o0 = __builtin_amdgcn_mfma_f32_32x32x16_bf16(pa, *(bf16x8*)&v0, o0, 0, 0, 0);
          u32x4 v1 = *(const u32x4*)&Vt2[(size_t)(32 + l31) * 65 + kpb];
          o1 = __builtin_amdgcn_mfma_f32_32x32x16_bf16(pa, *(bf16x8*)&v1, o1, 0, 0, 0);
        }
      }
    }
    __syncthreads();
#pragma unroll
    for (int p = 0; p < 4; ++p) vcur[p] = vnx[p];
  }

#pragma unroll
  for (int r = 0; r < 16; ++r) {
    int qp = (r & 3) + 8 * (r >> 2) + 4 * hi;
    float ls = __shfl(l_r, qp, 64);
    float inv = __builtin_amdgcn_rcpf(ls);
    int trow = s * 1024 + qb * 128 + w * 32 + qp;
    attnout[(size_t)trow * 1024 + h * 64 + l31]      = f2bf(o0[r] * inv);
    attnout[(size_t)trow * 1024 + h * 64 + 32 + l31] = f2bf(o1[r] * inv);
  }
}

// ---------------- host launch ----------------
extern "C" void kernel_launch(void* const* d_in, const int* in_sizes, int n_in,
                              void* d_out, int out_size, void* d_ws, size_t ws_size,
                              hipStream_t stream) {
  const float* hs = (const float*)d_in[0];
  const float* Wq = (const float*)d_in[2];
  const float* bq = (const float*)d_in[3];
  const float* Wk = (const float*)d_in[4];
  const float* Wv = (const float*)d_in[5];
  const float* bv = (const float*)d_in[6];
  const float* Wo = (const float*)d_in[7];
  const float* bo = (const float*)d_in[8];

  char* ws = (char*)d_ws;
  u16* Xb    = (u16*)ws;
  u16* Wqkv  = (u16*)(ws + 16777216);
  u16* Wob   = (u16*)(ws + 23068672);
  float* bqk = (float*)(ws + 25165824);
  u16* qkv   = (u16*)(ws + 25178112);
  u16* attn  = (u16*)(ws + 75509760);

  cvt_all<<<2048, 256, 0, stream>>>(hs, Wq, Wk, Wv, Wo, bq, bv, Xb, Wqkv, Wob, bqk);

  gemm8p<0><<<768, 512, 0, stream>>>(Xb, Wqkv, bqk, qkv, 8192, 3072, 1024, 12);

  attn_kernel<<<1024, 256, 0, stream>>>(qkv, attn);

  gemm8p<1><<<256, 512, 0, stream>>>(attn, Wob, bo, d_out, 8192, 1024, 1024, 4);
}